// Round 12
// baseline (166.859 us; speedup 1.0000x reference)
//
#include <hip/hip_runtime.h>
#include <math.h>

#define B_   2
#define S_   2048
#define D_   1024
#define H_   16
#define KH_  4
#define DK_  64

using bf16x8 = __attribute__((ext_vector_type(8))) short;
using bf16x4 = __attribute__((ext_vector_type(4))) short;
using f32x4  = __attribute__((ext_vector_type(4))) float;
using f32x2  = __attribute__((ext_vector_type(2))) float;
using u32x4  = __attribute__((ext_vector_type(4))) unsigned int;
using u32x2  = __attribute__((ext_vector_type(2))) unsigned int;

__device__ inline unsigned short f2bf(float f) {
    unsigned u = __float_as_uint(f);
    u += 0x7FFFu + ((u >> 16) & 1u);          // RNE
    return (unsigned short)(u >> 16);
}
__device__ inline float bf2f(unsigned short u) {
    return __uint_as_float(((unsigned)u) << 16);
}

#ifdef __has_builtin
#if __has_builtin(__builtin_amdgcn_cvt_pk_bf16_f32)
#define PKBF16 1
#endif
#if __has_builtin(__builtin_amdgcn_exp2f)
#define NEXP2 1
#endif
#endif
__device__ inline unsigned pk2bf(float a, float b) {
#ifdef PKBF16
    auto r = __builtin_amdgcn_cvt_pk_bf16_f32(a, b);
    unsigned u; __builtin_memcpy(&u, &r, 4);
    return u;
#else
    return (unsigned)f2bf(a) | ((unsigned)f2bf(b) << 16);
#endif
}
// single v_exp_f32 (no OCML denormal wrapper); exp2(-inf)=0, FTZ harmless here
__device__ inline float fexp2(float x) {
#ifdef NEXP2
    return __builtin_amdgcn_exp2f(x);
#else
    return exp2f(x);
#endif
}

// async global->LDS DMA, 16B per lane, dest = wave-uniform base + lane*16
#define GL16(gp, lp) __builtin_amdgcn_global_load_lds( \
    (const __attribute__((address_space(1))) unsigned int*)(gp), \
    (__attribute__((address_space(3))) unsigned int*)(lp), 16, 0, 0)

// ---------------------------------------------------------------------------
// Fused prep: blocks [0,2048) cast x fp32->bf16; [2048,2688) transpose+cast
// the four weight matrices; [2688,2944) build the rope sincos table
// sct[s][d] = {cos,sin}(s * 10000^{-d/32}) for s<2048, d<32 (512 KB).
// ---------------------------------------------------------------------------
__global__ __launch_bounds__(256) void prep_kernel(
    const float* __restrict__ x,
    const float* __restrict__ Wq, const float* __restrict__ Wk,
    const float* __restrict__ Wv, const float* __restrict__ Wo,
    unsigned short* __restrict__ xb,
    unsigned short* __restrict__ WqkvT,
    unsigned short* __restrict__ WoT,
    float* __restrict__ sct)
{
    __shared__ float T[64][65];
    const int t = threadIdx.x;
    int bx = blockIdx.x;

    if (bx < 2048) {                           // cast: 2048*256*8 = 4194304 el
        const int i = bx * 256 + t;
        f32x4 a = *(const f32x4*)(x + (long)i * 8);
        f32x4 b = *(const f32x4*)(x + (long)i * 8 + 4);
        bf16x8 o;
        o[0] = (short)f2bf(a[0]); o[1] = (short)f2bf(a[1]);
        o[2] = (short)f2bf(a[2]); o[3] = (short)f2bf(a[3]);
        o[4] = (short)f2bf(b[0]); o[5] = (short)f2bf(b[1]);
        o[6] = (short)f2bf(b[2]); o[7] = (short)f2bf(b[3]);
        *(bf16x8*)(xb + (long)i * 8) = o;
        return;
    }
    if (bx >= 2688) {                          // sincos table: 256 blk = 65536
        const int idx = (bx - 2688) * 256 + t;
        const int s = idx >> 5, d = idx & 31;
        const float theta = exp2f(-(float)d * (13.287712379549449f / 32.0f));
        const float f = (float)s * theta;
        sct[(long)idx * 2]     = cosf(f);
        sct[(long)idx * 2 + 1] = sinf(f);
        return;
    }
    bx -= 2048;
    const float* in; unsigned short* out; int C;
    if (bx < 256)      { in = Wq; out = WqkvT;               C = 1024; }
    else if (bx < 320) { in = Wk; out = WqkvT + 1024 * 1024; C = 256;  bx -= 256; }
    else if (bx < 384) { in = Wv; out = WqkvT + 1280 * 1024; C = 256;  bx -= 320; }
    else               { in = Wo; out = WoT;                 C = 1024; bx -= 384; }
    const int R  = 1024, nr = 16;
    const int r0 = (bx % nr) * 64;
    const int c0 = (bx / nr) * 64;
    {
        const int r  = t >> 2;
        const int cq = (t & 3) * 16;
        const float* src = in + (long)(r0 + r) * C + c0 + cq;
        #pragma unroll
        for (int i = 0; i < 4; ++i) {
            f32x4 v = *(const f32x4*)(src + i * 4);
            T[r][cq + i * 4 + 0] = v[0];
            T[r][cq + i * 4 + 1] = v[1];
            T[r][cq + i * 4 + 2] = v[2];
            T[r][cq + i * 4 + 3] = v[3];
        }
    }
    __syncthreads();
    {
        const int c  = t >> 2;
        const int rq = (t & 3) * 16;
        bf16x8 p0, p1;
        #pragma unroll
        for (int i = 0; i < 8; ++i) {
            p0[i] = (short)f2bf(T[rq + i][c]);
            p1[i] = (short)f2bf(T[rq + 8 + i][c]);
        }
        unsigned short* dst = out + (long)(c0 + c) * R + r0 + rq;
        *(bf16x8*)dst       = p0;
        *(bf16x8*)(dst + 8) = p1;
    }
}

// ---------------------------------------------------------------------------
// bf16 MFMA GEMM, 64x128 tile, BK=64 (round 7 WIN: halved barrier count).
// Round 9 WIN: BF16OUT=1 fuses ROPE into the epilogue; Q/K -> qbuf/kbuf.
// Round 11 WIN: V waves write TRANSPOSED directly to vbuf (B,KH,DK,S).
// BF16OUT=0: fp32 out + bias (out-proj), unchanged.
// ---------------------------------------------------------------------------
template<bool BF16OUT>
__global__ __launch_bounds__(256) void gemm64_kernel(
    const unsigned short* __restrict__ A,    // [M,K] bf16
    const unsigned short* __restrict__ Bt,   // [N,K] bf16
    const float* __restrict__ b0,
    const float* __restrict__ b1,
    const float* __restrict__ b2,
    float* __restrict__ outf,
    unsigned short* __restrict__ outb,       // BF16OUT=1: vbuf (B,KH,DK,S)
    unsigned short* __restrict__ qbuf,
    unsigned short* __restrict__ kbuf,
    const float* __restrict__ sct,
    int N, int K)
{
    __shared__ unsigned short As[2][64][64];
    __shared__ unsigned short Bs[2][128][64];

    const int t  = threadIdx.x;
    const int m0 = blockIdx.x * 64;
    const int n0 = blockIdx.y * 128;

    const int w    = t >> 6;
    const int lane = t & 63;
    const int n    = lane & 15;
    const int quad = lane >> 4;
    const int wm   = (w >> 1) * 32;
    const int wn   = (w & 1) * 64;

    const int sr8 = lane >> 3;                   // 0..7 (staged row within 8)
    const int gch = (lane & 7) ^ sr8;            // inverse-swizzled src chunk

    const unsigned short* gA = A  + (long)(m0 + w * 8 + sr8) * K + gch * 8;
    const unsigned short* gB = Bt + (long)(n0 + w * 8 + sr8) * K + gch * 8;

    // stage K-slice [kk,kk+64) into buffer buf
    #define STAGE(buf, kk)                                              \
    do {                                                                \
        GL16(gA + (kk),              &As[buf][w * 8][0]);               \
        GL16(gA + 32 * K + (kk),     &As[buf][w * 8 + 32][0]);          \
        GL16(gB + (kk),              &Bs[buf][w * 8][0]);               \
        GL16(gB + 32 * K + (kk),     &Bs[buf][w * 8 + 32][0]);          \
        GL16(gB + 64 * K + (kk),     &Bs[buf][w * 8 + 64][0]);          \
        GL16(gB + 96 * K + (kk),     &Bs[buf][w * 8 + 96][0]);          \
    } while (0)

    STAGE(0, 0);

    f32x4 acc[2][4];
    #pragma unroll
    for (int i = 0; i < 2; ++i)
        #pragma unroll
        for (int j = 0; j < 4; ++j) acc[i][j] = 0.0f;

    const int n7 = n & 7;

    for (int k0 = 0; k0 < K; k0 += 64) {
        const int cur = (k0 >> 6) & 1;
        __syncthreads();                 // drains DMA -> buf[cur] ready
        if (k0 + 64 < K) STAGE(cur ^ 1, k0 + 64);

        #pragma unroll
        for (int kp = 0; kp < 2; ++kp) {
            const int ca = ((kp * 4 + quad) ^ n7) * 8;
            bf16x8 af[2], bfr[4];
            #pragma unroll
            for (int i = 0; i < 2; ++i)
                af[i] = *(const bf16x8*)&As[cur][wm + i * 16 + n][ca];
            #pragma unroll
            for (int j = 0; j < 4; ++j)
                bfr[j] = *(const bf16x8*)&Bs[cur][wn + j * 16 + n][ca];
            #pragma unroll
            for (int mi = 0; mi < 2; ++mi)
                #pragma unroll
                for (int ni = 0; ni < 4; ++ni)
                    acc[mi][ni] = __builtin_amdgcn_mfma_f32_16x16x32_bf16(
                        af[mi], bfr[ni], acc[mi][ni], 0, 0, 0);
        }
    }
    #undef STAGE

    if (BF16OUT) {
        const int colbase = n0 + wn;             // wave's 64-col head block
        if (colbase < 1280) {                    // Q or K: rope in-register
            const bool isQ = colbase < 1024;
            const float scl = isQ ? 0.1803368801111606f : 1.0f;
            const int hh = isQ ? (colbase >> 6) : ((colbase - 1024) >> 6);
            const int HH = isQ ? H_ : KH_;
            unsigned short* obase = isQ ? qbuf : kbuf;
            const int gn0 = colbase + n;
            const float bA = isQ ? b0[gn0]      : b1[gn0 - 1024];
            const float bB = isQ ? b0[gn0 + 16] : b1[gn0 - 1008];
            const float bC = isQ ? b0[gn0 + 32] : b1[gn0 - 992];
            const float bD = isQ ? b0[gn0 + 48] : b1[gn0 - 976];
            #pragma unroll
            for (int mi = 0; mi < 2; ++mi) {
                #pragma unroll
                for (int r = 0; r < 4; ++r) {
                    const int gm = m0 + wm + mi * 16 + quad * 4 + r;
                    const int bb = gm >> 11, s = gm & (S_ - 1);
                    const f32x2 t0 = *(const f32x2*)(sct + ((long)s * 32 + n) * 2);
                    const f32x2 t1 = *(const f32x2*)(sct + ((long)s * 32 + 16 + n) * 2);
                    const float c0 = t0[0] * scl, s0v = t0[1] * scl;
                    const float c1 = t1[0] * scl, s1v = t1[1] * scl;
                    const float x1 = acc[mi][0][r] + bA;
                    const float y1 = acc[mi][1][r] + bB;
                    const float x2 = acc[mi][2][r] + bC;
                    const float y2 = acc[mi][3][r] + bD;
                    unsigned short* dst =
                        obase + ((long)(bb * HH + hh) * S_ + s) * DK_;
                    dst[n]      = f2bf(x1 * c0 - x2 * s0v);
                    dst[16 + n] = f2bf(y1 * c1 - y2 * s1v);
                    dst[32 + n] = f2bf(x2 * c0 + x1 * s0v);
                    dst[48 + n] = f2bf(y2 * c1 + y1 * s1v);
                }
            }
        } else {                                 // V: transposed write to vbuf
            const int hv = (colbase - 1280) >> 6;        // 0..3
            #pragma unroll
            for (int mi = 0; mi < 2; ++mi) {
                const int gm0 = m0 + wm + mi * 16 + quad * 4;
                const int bb  = gm0 >> 11;
                const int s0v = gm0 & (S_ - 1);
                #pragma unroll
                for (int ni = 0; ni < 4; ++ni) {
                    const int d = ni * 16 + n;
                    const float bias = b2[(colbase - 1280) + d];
                    bf16x4 o;
                    o[0] = (short)f2bf(acc[mi][ni][0] + bias);
                    o[1] = (short)f2bf(acc[mi][ni][1] + bias);
                    o[2] = (short)f2bf(acc[mi][ni][2] + bias);
                    o[3] = (short)f2bf(acc[mi][ni][3] + bias);
                    unsigned short* dst = outb +
                        ((long)((bb * KH_ + hv) * DK_ + d)) * S_ + s0v;
                    *(bf16x4*)dst = o;
                }
            }
        }
    } else {
        #pragma unroll
        for (int mi = 0; mi < 2; ++mi) {
            #pragma unroll
            for (int r = 0; r < 4; ++r) {
                const int gm = m0 + wm + mi * 16 + quad * 4 + r;
                #pragma unroll
                for (int ni = 0; ni < 4; ++ni) {
                    const int gn = n0 + wn + ni * 16 + n;
                    outf[(long)gm * N + gn] = acc[mi][ni][r] + b0[gn];
                }
            }
        }
    }
}

// ---------------------------------------------------------------------------
// bf16 MFMA causal flash attention, v14: KVBLK=128 (halve barrier count).
// Round 12: per-CU tile-iterations 36 -> 17; each __syncthreads aligns all
// 8 waves + drains — the same structural cost BK=32->64 removed from the
// GEMM (round 7, -12%). Staged bytes/barrier double, MFMA/barrier doubles.
// LDS 48->80KB, still 2 blocks/CU (= grid); __launch_bounds__(512,4) caps
// VGPR at 128 (est. ~110). Causal: boundary is always the LAST tile; wave
// wv computes ct<=wv there (uncomputed sc = -inf -> exp 0); PV skips
// all-zero k-slices (2ks<=wv). v13's V-permutation generalizes: vb0(c)
// formula already covers chunks 0..15; piece-B offset = piece-A + 64.
// ---------------------------------------------------------------------------
__global__ __launch_bounds__(512, 4) void attn_kernel(
    const unsigned short* __restrict__ qb,   // (B,H,S,DK), pre-scaled
    const unsigned short* __restrict__ kbf,  // (B,KH,S,DK)
    const unsigned short* __restrict__ vT,   // (B,KH,DK,S)
    unsigned short* __restrict__ ot)         // (B,S,H*DK)
{
    __shared__ __align__(16) unsigned short Ks[2][128][64];
    __shared__ __align__(16) unsigned short Vs[2][64][128];
    __shared__ __align__(16) unsigned short Ps[8][16][64];

    const int tid = threadIdx.x;
    const int bx  = blockIdx.x;

    // co-resident {p,p+256}: same bh, a = {15-g, g} -> 17 tile-iters/CU
    const int j  = bx >> 8;                   // half 0..1
    const int p  = bx & 255;
    const int g  = p >> 5;                    // 0..7
    const int bh = p & 31;
    const int a  = j ? g : (15 - g);          // heavy first

    const int b   = bh >> 4, h = bh & 15;
    const int kh  = h >> 2;
    const int q0  = a * 128;

    const int wv   = tid >> 6;                // 0..7
    const int lane = tid & 63;
    const int n    = lane & 15;
    const int quad = lane >> 4;
    const int xk   = n & 7;                   // row-derived XOR key

    const unsigned short* qp =
        qb + ((long)(b * H_ + h) * S_ + q0 + wv * 16 + n) * DK_;
    const bf16x8 qa0 = *(const bf16x8*)(qp + quad * 8);
    const bf16x8 qa1 = *(const bf16x8*)(qp + 32 + quad * 8);

    f32x4 O[4];                       // O^T[d = dt*16+quad*4+r][q = n]
    #pragma unroll
    for (int dt = 0; dt < 4; ++dt) O[dt] = 0.0f;
    float lsum = 0.f;

    const unsigned short* kbase = kbf + (long)(b * KH_ + kh) * S_ * DK_;
    const unsigned short* vbase = vT  + (long)(b * KH_ + kh) * DK_ * S_;

    const int ntiles = a + 1;                 // 128-wide K/V tiles
    const int srow = tid >> 3;                // 0..63
    const int lc   = tid & 7;                 // logical 16B chunk (piece A)
    const int sc8  = lc * 8;                  // global short offset
    const int rk   = srow & 7;                // row XOR key (staging side)
    const int pcs  = (lc ^ rk) * 8;           // K: swizzled LDS short offset

    // V permuted staging (piece A: s 0..63, chunk lc; piece B: +64)
    const int vb0  = (lc & 1) * 16 + ((lc >> 1) & 1) * 4 + (lc >> 2) * 32;
    const int vc1  = vb0 >> 3;                // logical chunk of half A1
    const int voff = vb0 & 7;                 // short offset within chunk
    const int vp1  = ((vc1 ^ rk) * 8) + voff;
    const int vp2  = (((vc1 + 1) ^ rk) * 8) + voff;

    u32x4 kr0 = *(const u32x4*)(kbase + (long)srow * DK_ + sc8);
    u32x4 kr1 = *(const u32x4*)(kbase + (long)(64 + srow) * DK_ + sc8);
    u32x4 vr0 = *(const u32x4*)(vbase + (long)srow * S_ + sc8);
    u32x4 vr1 = *(const u32x4*)(vbase + (long)srow * S_ + 64 + sc8);
    {
        *(u32x4*)&Ks[0][srow][pcs]      = kr0;
        *(u32x4*)&Ks[0][64 + srow][pcs] = kr1;
        u32x2 h0, h1;
        h0[0] = vr0[0]; h0[1] = vr0[1];
        h1[0] = vr0[2]; h1[1] = vr0[3];
        *(u32x2*)&Vs[0][srow][vp1] = h0;
        *(u32x2*)&Vs[0][srow][vp2] = h1;
        h0[0] = vr1[0]; h0[1] = vr1[1];
        h1[0] = vr1[2]; h1[1] = vr1[3];
        *(u32x2*)&Vs[0][srow][vp1 + 64] = h0;
        *(u32x2*)&Vs[0][srow][vp2 + 64] = h1;
    }

    for (int u = 0; u < ntiles; ++u) {
        const int cur = u & 1;
        const int kb  = u * 128;
        const bool last = (u + 1 == ntiles);
        __syncthreads();

        if (!last) {
            const int kbn = kb + 128;
            kr0 = *(const u32x4*)(kbase + (long)(kbn + srow) * DK_ + sc8);
            kr1 = *(const u32x4*)(kbase + (long)(kbn + 64 + srow) * DK_ + sc8);
            vr0 = *(const u32x4*)(vbase + (long)srow * S_ + kbn + sc8);
            vr1 = *(const u32x4*)(vbase + (long)srow * S_ + kbn + 64 + sc8);
        }

        const int ctmax = last ? wv : 7;      // causal sub-tile bound

        // ---- S^T = K @ Q^T (pre-scaled, log2 domain) ----
        f32x4 sc[8];
        #pragma unroll
        for (int ct = 0; ct < 8; ++ct) {
            if (ct <= ctmax) {
                const bf16x8 kf0 =
                    *(const bf16x8*)&Ks[cur][ct * 16 + n][(quad ^ xk) * 8];
                const bf16x8 kf1 =
                    *(const bf16x8*)&Ks[cur][ct * 16 + n][((quad + 4) ^ xk) * 8];
                f32x4 c = 0.0f;
                c = __builtin_amdgcn_mfma_f32_16x16x32_bf16(kf0, qa0, c, 0, 0, 0);
                c = __builtin_amdgcn_mfma_f32_16x16x32_bf16(kf1, qa1, c, 0, 0, 0);
                sc[ct] = c;
            } else {
                sc[ct] = -INFINITY;
            }
        }

        // ---- causal mask on the boundary tile ----
        if (last) {
            const int qg = q0 + wv * 16 + n;
            #pragma unroll
            for (int ct = 0; ct < 8; ++ct) {
                if (ct <= ctmax) {
                    const int kq = kb + ct * 16 + quad * 4;
                    #pragma unroll
                    for (int r = 0; r < 4; ++r)
                        if (kq + r > qg) sc[ct][r] = -INFINITY;
                }
            }
        }

        // ---- max-free softmax ----
        f32x4 rs4 = 0.0f;
        #pragma unroll
        for (int ct = 0; ct < 8; ++ct) {
            #pragma unroll
            for (int r = 0; r < 4; ++r) {
                const float p2 = fexp2(sc[ct][r]);   // -inf -> 0
                sc[ct][r] = p2;
                rs4[r] += p2;
            }
        }
        lsum += (rs4[0] + rs4[1]) + (rs4[2] + rs4[3]);

        // ---- P -> PV B-frags in-register (no LDS round-trip) ----
        bf16x8 pb[4];
        #pragma unroll
        for (int ks = 0; ks < 4; ++ks) {
            u32x4 pw;
            pw[0] = pk2bf(sc[2 * ks][0],     sc[2 * ks][1]);
            pw[1] = pk2bf(sc[2 * ks][2],     sc[2 * ks][3]);
            pw[2] = pk2bf(sc[2 * ks + 1][0], sc[2 * ks + 1][1]);
            pw[3] = pk2bf(sc[2 * ks + 1][2], sc[2 * ks + 1][3]);
            __builtin_memcpy(&pb[ks], &pw, 16);
        }

        // ---- O^T += V^T @ P^T (Vs layout matches pb slot order) ----
        #pragma unroll
        for (int dt = 0; dt < 4; ++dt) {
            #pragma unroll
            for (int ks = 0; ks < 4; ++ks) {
                if (!last || 2 * ks <= wv) {
                    const bf16x8 av = *(const bf16x8*)
                        &Vs[cur][dt * 16 + n][((ks * 4 + quad) ^ xk) * 8];
                    O[dt] = __builtin_amdgcn_mfma_f32_16x16x32_bf16(
                        av, pb[ks], O[dt], 0, 0, 0);
                }
            }
        }

        if (!last) {
            const int nb = cur ^ 1;
            *(u32x4*)&Ks[nb][srow][pcs]      = kr0;
            *(u32x4*)&Ks[nb][64 + srow][pcs] = kr1;
            u32x2 h0, h1;
            h0[0] = vr0[0]; h0[1] = vr0[1];
            h1[0] = vr0[2]; h1[1] = vr0[3];
            *(u32x2*)&Vs[nb][srow][vp1] = h0;
            *(u32x2*)&Vs[nb][srow][vp2] = h1;
            h0[0] = vr1[0]; h0[1] = vr1[1];
            h1[0] = vr1[2]; h1[1] = vr1[3];
            *(u32x2*)&Vs[nb][srow][vp1 + 64] = h0;
            *(u32x2*)&Vs[nb][srow][vp2 + 64] = h1;
        }
    }

    // ---- epilogue ----
    lsum += __shfl_xor(lsum, 16);
    lsum += __shfl_xor(lsum, 32);
    const float inv = 1.0f / lsum;
    #pragma unroll
    for (int dt = 0; dt < 4; ++dt) {
        u32x2 pw;
        pw[0] = pk2bf(O[dt][0] * inv, O[dt][1] * inv);
        pw[1] = pk2bf(O[dt][2] * inv, O[dt][3] * inv);
        const int pc = ((2 * dt + (quad >> 1)) ^ xk) * 8 + (quad & 1) * 4;
        *(u32x2*)&Ps[wv][n][pc] = pw;
    }
    __builtin_amdgcn_s_waitcnt(0);            // lgkmcnt for own-wave Ps writes
    const int fr = lane >> 3;                        // 0..7
    const int c8l = lane & 7;                        // logical chunk
    #pragma unroll
    for (int it = 0; it < 2; ++it) {
        const int row = it * 8 + fr;                 // 0..15, row&7 == fr
        const int q   = q0 + wv * 16 + row;
        unsigned short* op = ot + ((long)(b * S_ + q) * H_ + h) * DK_ + c8l * 8;
        *(bf16x8*)op = *(const bf16x8*)&Ps[wv][row][(c8l ^ fr) * 8];
    }
}

// ---------------------------------------------------------------------------
extern "C" void kernel_launch(void* const* d_in, const int* in_sizes, int n_in,
                              void* d_out, int out_size, void* d_ws, size_t ws_size,
                              hipStream_t stream)
{
    const float* x  = (const float*)d_in[0];
    const float* Wq = (const float*)d_in[2];
    const float* bq = (const float*)d_in[3];
    const float* Wk = (const float*)d_in[4];
    const float* bk = (const float*)d_in[5];
    const float* Wv = (const float*)d_in[6];
    const float* bv = (const float*)d_in[7];
    const float* Wo = (const float*)d_in[8];
    const float* bo = (const float*)d_in[9];
    float* out = (float*)d_out;

    // Workspace (bf16 shorts + f32 table), ~39.3 MB. ob aliases qkvm.
    unsigned short* ws    = (unsigned short*)d_ws;
    unsigned short* xb    = ws;                   // 4194304
    unsigned short* qkvm  = xb + 4194304;         // 6291456  (ob alias only)
    unsigned short* qbuf  = qkvm + 6291456;       // 4194304
    unsigned short* kbuf  = qbuf + 4194304;       // 1048576
    unsigned short* vbuf  = kbuf + 1048576;       // 1048576
    unsigned short* WqkvT = vbuf + 1048576;       // 1572864
    unsigned short* WoT   = WqkvT + 1572864;      // 1048576
    float*          sct   = (float*)(WoT + 1048576); // 131072 floats (512KB)
    unsigned short* ob    = qkvm;                 // alias

    prep_kernel<<<2944, 256, 0, stream>>>(x, Wq, Wk, Wv, Wo, xb, WqkvT, WoT, sct);

    gemm64_kernel<true><<<dim3(64, 12), 256, 0, stream>>>(
        xb, WqkvT, bq, bk, bv, nullptr, vbuf, qbuf, kbuf, sct, 1536, 1024);

    attn_kernel<<<512, 512, 0, stream>>>(qbuf, kbuf, vbuf, ob);

    gemm64_kernel<false><<<dim3(64, 8), 256, 0, stream>>>(
        ob, WoT, bo, nullptr, nullptr, out, nullptr, nullptr, nullptr, nullptr,
        1024, 1024);
}

// Round 13
// 162.227 us; speedup vs baseline: 1.0285x; 1.0285x over previous
//
#include <hip/hip_runtime.h>
#include <math.h>

#define B_   2
#define S_   2048
#define D_   1024
#define H_   16
#define KH_  4
#define DK_  64

using bf16x8 = __attribute__((ext_vector_type(8))) short;
using bf16x4 = __attribute__((ext_vector_type(4))) short;
using f32x4  = __attribute__((ext_vector_type(4))) float;
using f32x2  = __attribute__((ext_vector_type(2))) float;
using u32x4  = __attribute__((ext_vector_type(4))) unsigned int;
using u32x2  = __attribute__((ext_vector_type(2))) unsigned int;

__device__ inline unsigned short f2bf(float f) {
    unsigned u = __float_as_uint(f);
    u += 0x7FFFu + ((u >> 16) & 1u);          // RNE
    return (unsigned short)(u >> 16);
}
__device__ inline float bf2f(unsigned short u) {
    return __uint_as_float(((unsigned)u) << 16);
}

#ifdef __has_builtin
#if __has_builtin(__builtin_amdgcn_cvt_pk_bf16_f32)
#define PKBF16 1
#endif
#if __has_builtin(__builtin_amdgcn_exp2f)
#define NEXP2 1
#endif
#endif
__device__ inline unsigned pk2bf(float a, float b) {
#ifdef PKBF16
    auto r = __builtin_amdgcn_cvt_pk_bf16_f32(a, b);
    unsigned u; __builtin_memcpy(&u, &r, 4);
    return u;
#else
    return (unsigned)f2bf(a) | ((unsigned)f2bf(b) << 16);
#endif
}
// single v_exp_f32 (no OCML denormal wrapper); exp2(-inf)=0, FTZ harmless here
__device__ inline float fexp2(float x) {
#ifdef NEXP2
    return __builtin_amdgcn_exp2f(x);
#else
    return exp2f(x);
#endif
}

// async global->LDS DMA, 16B per lane, dest = wave-uniform base + lane*16
#define GL16(gp, lp) __builtin_amdgcn_global_load_lds( \
    (const __attribute__((address_space(1))) unsigned int*)(gp), \
    (__attribute__((address_space(3))) unsigned int*)(lp), 16, 0, 0)

// ---------------------------------------------------------------------------
// Fused prep: blocks [0,2048) cast x fp32->bf16; [2048,2688) transpose+cast
// the four weight matrices; [2688,2944) build the rope sincos table
// sct[s][d] = {cos,sin}(s * 10000^{-d/32}) for s<2048, d<32 (512 KB).
// ---------------------------------------------------------------------------
__global__ __launch_bounds__(256) void prep_kernel(
    const float* __restrict__ x,
    const float* __restrict__ Wq, const float* __restrict__ Wk,
    const float* __restrict__ Wv, const float* __restrict__ Wo,
    unsigned short* __restrict__ xb,
    unsigned short* __restrict__ WqkvT,
    unsigned short* __restrict__ WoT,
    float* __restrict__ sct)
{
    __shared__ float T[64][65];
    const int t = threadIdx.x;
    int bx = blockIdx.x;

    if (bx < 2048) {                           // cast: 2048*256*8 = 4194304 el
        const int i = bx * 256 + t;
        f32x4 a = *(const f32x4*)(x + (long)i * 8);
        f32x4 b = *(const f32x4*)(x + (long)i * 8 + 4);
        bf16x8 o;
        o[0] = (short)f2bf(a[0]); o[1] = (short)f2bf(a[1]);
        o[2] = (short)f2bf(a[2]); o[3] = (short)f2bf(a[3]);
        o[4] = (short)f2bf(b[0]); o[5] = (short)f2bf(b[1]);
        o[6] = (short)f2bf(b[2]); o[7] = (short)f2bf(b[3]);
        *(bf16x8*)(xb + (long)i * 8) = o;
        return;
    }
    if (bx >= 2688) {                          // sincos table: 256 blk = 65536
        const int idx = (bx - 2688) * 256 + t;
        const int s = idx >> 5, d = idx & 31;
        const float theta = exp2f(-(float)d * (13.287712379549449f / 32.0f));
        const float f = (float)s * theta;
        sct[(long)idx * 2]     = cosf(f);
        sct[(long)idx * 2 + 1] = sinf(f);
        return;
    }
    bx -= 2048;
    const float* in; unsigned short* out; int C;
    if (bx < 256)      { in = Wq; out = WqkvT;               C = 1024; }
    else if (bx < 320) { in = Wk; out = WqkvT + 1024 * 1024; C = 256;  bx -= 256; }
    else if (bx < 384) { in = Wv; out = WqkvT + 1280 * 1024; C = 256;  bx -= 320; }
    else               { in = Wo; out = WoT;                 C = 1024; bx -= 384; }
    const int R  = 1024, nr = 16;
    const int r0 = (bx % nr) * 64;
    const int c0 = (bx / nr) * 64;
    {
        const int r  = t >> 2;
        const int cq = (t & 3) * 16;
        const float* src = in + (long)(r0 + r) * C + c0 + cq;
        #pragma unroll
        for (int i = 0; i < 4; ++i) {
            f32x4 v = *(const f32x4*)(src + i * 4);
            T[r][cq + i * 4 + 0] = v[0];
            T[r][cq + i * 4 + 1] = v[1];
            T[r][cq + i * 4 + 2] = v[2];
            T[r][cq + i * 4 + 3] = v[3];
        }
    }
    __syncthreads();
    {
        const int c  = t >> 2;
        const int rq = (t & 3) * 16;
        bf16x8 p0, p1;
        #pragma unroll
        for (int i = 0; i < 8; ++i) {
            p0[i] = (short)f2bf(T[rq + i][c]);
            p1[i] = (short)f2bf(T[rq + 8 + i][c]);
        }
        unsigned short* dst = out + (long)(c0 + c) * R + r0 + rq;
        *(bf16x8*)dst       = p0;
        *(bf16x8*)(dst + 8) = p1;
    }
}

// ---------------------------------------------------------------------------
// bf16 MFMA GEMM, 64x128 tile, BK=64 (round 7 WIN: halved barrier count).
// Round 9 WIN: BF16OUT=1 fuses ROPE into the epilogue; Q/K -> qbuf/kbuf.
// Round 11 WIN: V waves write TRANSPOSED directly to vbuf (B,KH,DK,S).
// BF16OUT=0: fp32 out + bias (out-proj), unchanged.
// ---------------------------------------------------------------------------
template<bool BF16OUT>
__global__ __launch_bounds__(256) void gemm64_kernel(
    const unsigned short* __restrict__ A,    // [M,K] bf16
    const unsigned short* __restrict__ Bt,   // [N,K] bf16
    const float* __restrict__ b0,
    const float* __restrict__ b1,
    const float* __restrict__ b2,
    float* __restrict__ outf,
    unsigned short* __restrict__ outb,       // BF16OUT=1: vbuf (B,KH,DK,S)
    unsigned short* __restrict__ qbuf,
    unsigned short* __restrict__ kbuf,
    const float* __restrict__ sct,
    int N, int K)
{
    __shared__ unsigned short As[2][64][64];
    __shared__ unsigned short Bs[2][128][64];

    const int t  = threadIdx.x;
    const int m0 = blockIdx.x * 64;
    const int n0 = blockIdx.y * 128;

    const int w    = t >> 6;
    const int lane = t & 63;
    const int n    = lane & 15;
    const int quad = lane >> 4;
    const int wm   = (w >> 1) * 32;
    const int wn   = (w & 1) * 64;

    const int sr8 = lane >> 3;                   // 0..7 (staged row within 8)
    const int gch = (lane & 7) ^ sr8;            // inverse-swizzled src chunk

    const unsigned short* gA = A  + (long)(m0 + w * 8 + sr8) * K + gch * 8;
    const unsigned short* gB = Bt + (long)(n0 + w * 8 + sr8) * K + gch * 8;

    // stage K-slice [kk,kk+64) into buffer buf
    #define STAGE(buf, kk)                                              \
    do {                                                                \
        GL16(gA + (kk),              &As[buf][w * 8][0]);               \
        GL16(gA + 32 * K + (kk),     &As[buf][w * 8 + 32][0]);          \
        GL16(gB + (kk),              &Bs[buf][w * 8][0]);               \
        GL16(gB + 32 * K + (kk),     &Bs[buf][w * 8 + 32][0]);          \
        GL16(gB + 64 * K + (kk),     &Bs[buf][w * 8 + 64][0]);          \
        GL16(gB + 96 * K + (kk),     &Bs[buf][w * 8 + 96][0]);          \
    } while (0)

    STAGE(0, 0);

    f32x4 acc[2][4];
    #pragma unroll
    for (int i = 0; i < 2; ++i)
        #pragma unroll
        for (int j = 0; j < 4; ++j) acc[i][j] = 0.0f;

    const int n7 = n & 7;

    for (int k0 = 0; k0 < K; k0 += 64) {
        const int cur = (k0 >> 6) & 1;
        __syncthreads();                 // drains DMA -> buf[cur] ready
        if (k0 + 64 < K) STAGE(cur ^ 1, k0 + 64);

        #pragma unroll
        for (int kp = 0; kp < 2; ++kp) {
            const int ca = ((kp * 4 + quad) ^ n7) * 8;
            bf16x8 af[2], bfr[4];
            #pragma unroll
            for (int i = 0; i < 2; ++i)
                af[i] = *(const bf16x8*)&As[cur][wm + i * 16 + n][ca];
            #pragma unroll
            for (int j = 0; j < 4; ++j)
                bfr[j] = *(const bf16x8*)&Bs[cur][wn + j * 16 + n][ca];
            #pragma unroll
            for (int mi = 0; mi < 2; ++mi)
                #pragma unroll
                for (int ni = 0; ni < 4; ++ni)
                    acc[mi][ni] = __builtin_amdgcn_mfma_f32_16x16x32_bf16(
                        af[mi], bfr[ni], acc[mi][ni], 0, 0, 0);
        }
    }
    #undef STAGE

    if (BF16OUT) {
        const int colbase = n0 + wn;             // wave's 64-col head block
        if (colbase < 1280) {                    // Q or K: rope in-register
            const bool isQ = colbase < 1024;
            const float scl = isQ ? 0.1803368801111606f : 1.0f;
            const int hh = isQ ? (colbase >> 6) : ((colbase - 1024) >> 6);
            const int HH = isQ ? H_ : KH_;
            unsigned short* obase = isQ ? qbuf : kbuf;
            const int gn0 = colbase + n;
            const float bA = isQ ? b0[gn0]      : b1[gn0 - 1024];
            const float bB = isQ ? b0[gn0 + 16] : b1[gn0 - 1008];
            const float bC = isQ ? b0[gn0 + 32] : b1[gn0 - 992];
            const float bD = isQ ? b0[gn0 + 48] : b1[gn0 - 976];
            #pragma unroll
            for (int mi = 0; mi < 2; ++mi) {
                #pragma unroll
                for (int r = 0; r < 4; ++r) {
                    const int gm = m0 + wm + mi * 16 + quad * 4 + r;
                    const int bb = gm >> 11, s = gm & (S_ - 1);
                    const f32x2 t0 = *(const f32x2*)(sct + ((long)s * 32 + n) * 2);
                    const f32x2 t1 = *(const f32x2*)(sct + ((long)s * 32 + 16 + n) * 2);
                    const float c0 = t0[0] * scl, s0v = t0[1] * scl;
                    const float c1 = t1[0] * scl, s1v = t1[1] * scl;
                    const float x1 = acc[mi][0][r] + bA;
                    const float y1 = acc[mi][1][r] + bB;
                    const float x2 = acc[mi][2][r] + bC;
                    const float y2 = acc[mi][3][r] + bD;
                    unsigned short* dst =
                        obase + ((long)(bb * HH + hh) * S_ + s) * DK_;
                    dst[n]      = f2bf(x1 * c0 - x2 * s0v);
                    dst[16 + n] = f2bf(y1 * c1 - y2 * s1v);
                    dst[32 + n] = f2bf(x2 * c0 + x1 * s0v);
                    dst[48 + n] = f2bf(y2 * c1 + y1 * s1v);
                }
            }
        } else {                                 // V: transposed write to vbuf
            const int hv = (colbase - 1280) >> 6;        // 0..3
            #pragma unroll
            for (int mi = 0; mi < 2; ++mi) {
                const int gm0 = m0 + wm + mi * 16 + quad * 4;
                const int bb  = gm0 >> 11;
                const int s0v = gm0 & (S_ - 1);
                #pragma unroll
                for (int ni = 0; ni < 4; ++ni) {
                    const int d = ni * 16 + n;
                    const float bias = b2[(colbase - 1280) + d];
                    bf16x4 o;
                    o[0] = (short)f2bf(acc[mi][ni][0] + bias);
                    o[1] = (short)f2bf(acc[mi][ni][1] + bias);
                    o[2] = (short)f2bf(acc[mi][ni][2] + bias);
                    o[3] = (short)f2bf(acc[mi][ni][3] + bias);
                    unsigned short* dst = outb +
                        ((long)((bb * KH_ + hv) * DK_ + d)) * S_ + s0v;
                    *(bf16x4*)dst = o;
                }
            }
        }
    } else {
        #pragma unroll
        for (int mi = 0; mi < 2; ++mi) {
            #pragma unroll
            for (int r = 0; r < 4; ++r) {
                const int gm = m0 + wm + mi * 16 + quad * 4 + r;
                #pragma unroll
                for (int ni = 0; ni < 4; ++ni) {
                    const int gn = n0 + wn + ni * 16 + n;
                    outf[(long)gm * N + gn] = acc[mi][ni][r] + b0[gn];
                }
            }
        }
    }
}

// ---------------------------------------------------------------------------
// bf16 MFMA causal flash attention, v13 (round 10/11 state — best measured).
// Round 12's KVBLK=128 regressed (163.4 -> 166.9: sc[8] register doubling
// against the 128-VGPR cap + last-tile wave imbalance inside one barrier
// interval) -> reverted. Barrier-halving in attn falsified both directions
// (v9: occupancy loss; v14: register/imbalance loss); v13 is the local
// optimum for this decomposition.
// Structure: 8-wave blocks (512 thr), QBLK=128, staged K/V shared by 8
// waves; in-register P via consistent s-permutation of P slot order and V
// LDS layout (zero cross-lane ops); co-resident {p,p+256} share bh,
// a={15-g,g} -> uniform 36 tile-iters/CU.
// ---------------------------------------------------------------------------
__global__ __launch_bounds__(512) void attn_kernel(
    const unsigned short* __restrict__ qb,   // (B,H,S,DK), pre-scaled
    const unsigned short* __restrict__ kbf,  // (B,KH,S,DK)
    const unsigned short* __restrict__ vT,   // (B,KH,DK,S)
    unsigned short* __restrict__ ot)         // (B,S,H*DK)
{
    __shared__ __align__(16) unsigned short Ks[2][64][64];
    __shared__ __align__(16) unsigned short Vs[2][64][64];
    __shared__ __align__(16) unsigned short Ps[8][16][64];

    const int tid = threadIdx.x;
    const int bx  = blockIdx.x;

    // co-resident {p,p+256}: same bh, a = {15-g, g} -> 36 tile-iters/CU
    const int j  = bx >> 8;                   // half 0..1
    const int p  = bx & 255;
    const int g  = p >> 5;                    // 0..7
    const int bh = p & 31;
    const int a  = j ? g : (15 - g);          // heavy first

    const int b   = bh >> 4, h = bh & 15;
    const int kh  = h >> 2;
    const int q0  = a * 128;

    const int wv   = tid >> 6;                // 0..7
    const int lane = tid & 63;
    const int n    = lane & 15;
    const int quad = lane >> 4;
    const int xk   = n & 7;                   // row-derived XOR key

    const unsigned short* qp =
        qb + ((long)(b * H_ + h) * S_ + q0 + wv * 16 + n) * DK_;
    const bf16x8 qa0 = *(const bf16x8*)(qp + quad * 8);
    const bf16x8 qa1 = *(const bf16x8*)(qp + 32 + quad * 8);

    f32x4 O[4];                       // O^T[d = dt*16+quad*4+r][q = n]
    #pragma unroll
    for (int dt = 0; dt < 4; ++dt) O[dt] = 0.0f;
    float lsum = 0.f;

    const unsigned short* kbase = kbf + (long)(b * KH_ + kh) * S_ * DK_;
    const unsigned short* vbase = vT  + (long)(b * KH_ + kh) * DK_ * S_;

    const int ntiles = 2 * a + 2;
    const int ub     = 2 * a + (wv >> 2);     // boundary tile for this wave
    const int srow = tid >> 3;                // 0..63 (one row per thread)
    const int lc   = tid & 7;                 // logical 16B chunk
    const int sc8  = lc * 8;                  // global short offset
    const int rk   = srow & 7;                // row XOR key (staging side)
    const int pcs  = (lc ^ rk) * 8;           // K: swizzled LDS short offset

    // V permuted staging: s-chunk lc*8+e -> p pieces at vb0+{0..3} and
    // vb0+8+{0..3}, vb0 = (lc&1)*16 + ((lc>>1)&1)*4 + (lc>>2)*32
    const int vb0  = (lc & 1) * 16 + ((lc >> 1) & 1) * 4 + (lc >> 2) * 32;
    const int vc1  = vb0 >> 3;                // logical chunk of piece A
    const int voff = vb0 & 7;                 // short offset within chunk
    const int vp1  = ((vc1 ^ rk) * 8) + voff;
    const int vp2  = (((vc1 + 1) ^ rk) * 8) + voff;

    u32x4 kr = *(const u32x4*)(kbase + (long)srow * DK_ + sc8);
    u32x4 vr = *(const u32x4*)(vbase + (long)srow * S_ + sc8);
    *(u32x4*)&Ks[0][srow][pcs] = kr;
    {
        u32x2 va, vb2;
        va[0] = vr[0];  va[1] = vr[1];
        vb2[0] = vr[2]; vb2[1] = vr[3];
        *(u32x2*)&Vs[0][srow][vp1] = va;
        *(u32x2*)&Vs[0][srow][vp2] = vb2;
    }

    for (int u = 0; u < ntiles; ++u) {
        const int cur = u & 1;
        const int kb  = u * 64;
        __syncthreads();

        if (u + 1 < ntiles) {
            const int kbn = kb + 64;
            kr = *(const u32x4*)(kbase + (long)(kbn + srow) * DK_ + sc8);
            vr = *(const u32x4*)(vbase + (long)srow * S_ + kbn + sc8);
        }

        if (u <= ub) {                        // wave-uniform compute gate
            // ---- S^T = K @ Q^T (pre-scaled, log2 domain) ----
            f32x4 sc[4];
            #pragma unroll
            for (int ct = 0; ct < 4; ++ct) {
                const bf16x8 kf0 =
                    *(const bf16x8*)&Ks[cur][ct * 16 + n][(quad ^ xk) * 8];
                const bf16x8 kf1 =
                    *(const bf16x8*)&Ks[cur][ct * 16 + n][((quad + 4) ^ xk) * 8];
                f32x4 c = 0.0f;
                c = __builtin_amdgcn_mfma_f32_16x16x32_bf16(kf0, qa0, c, 0, 0, 0);
                c = __builtin_amdgcn_mfma_f32_16x16x32_bf16(kf1, qa1, c, 0, 0, 0);
                sc[ct] = c;
            }

            // ---- causal mask on the boundary tile ----
            if (u == ub) {
                const int qg = q0 + wv * 16 + n;
                #pragma unroll
                for (int ct = 0; ct < 4; ++ct) {
                    const int kq = kb + ct * 16 + quad * 4;
                    #pragma unroll
                    for (int r = 0; r < 4; ++r)
                        if (kq + r > qg) sc[ct][r] = -INFINITY;
                }
            }

            // ---- max-free softmax ----
            f32x4 rs4 = 0.0f;
            #pragma unroll
            for (int ct = 0; ct < 4; ++ct) {
                #pragma unroll
                for (int r = 0; r < 4; ++r) {
                    const float p2 = fexp2(sc[ct][r]);   // -inf -> 0
                    sc[ct][r] = p2;
                    rs4[r] += p2;
                }
            }
            lsum += (rs4[0] + rs4[1]) + (rs4[2] + rs4[3]);

            // ---- P -> PV B-frags in-register (no LDS round-trip) ----
            u32x4 pw0, pw1;
            pw0[0] = pk2bf(sc[0][0], sc[0][1]);
            pw0[1] = pk2bf(sc[0][2], sc[0][3]);
            pw0[2] = pk2bf(sc[1][0], sc[1][1]);
            pw0[3] = pk2bf(sc[1][2], sc[1][3]);
            pw1[0] = pk2bf(sc[2][0], sc[2][1]);
            pw1[1] = pk2bf(sc[2][2], sc[2][3]);
            pw1[2] = pk2bf(sc[3][0], sc[3][1]);
            pw1[3] = pk2bf(sc[3][2], sc[3][3]);
            bf16x8 pb0, pb1;
            __builtin_memcpy(&pb0, &pw0, 16);
            __builtin_memcpy(&pb1, &pw1, 16);

            // ---- O^T += V^T @ P^T (Vs layout matches pb slot order) ----
            #pragma unroll
            for (int dt = 0; dt < 4; ++dt) {
                const bf16x8 av0 =
                    *(const bf16x8*)&Vs[cur][dt * 16 + n][(quad ^ xk) * 8];
                const bf16x8 av1 =
                    *(const bf16x8*)&Vs[cur][dt * 16 + n][((quad + 4) ^ xk) * 8];
                O[dt] = __builtin_amdgcn_mfma_f32_16x16x32_bf16(av0, pb0, O[dt], 0, 0, 0);
                O[dt] = __builtin_amdgcn_mfma_f32_16x16x32_bf16(av1, pb1, O[dt], 0, 0, 0);
            }
        }

        if (u + 1 < ntiles) {
            const int nb = cur ^ 1;
            *(u32x4*)&Ks[nb][srow][pcs] = kr;
            u32x2 va, vb2;
            va[0] = vr[0];  va[1] = vr[1];
            vb2[0] = vr[2]; vb2[1] = vr[3];
            *(u32x2*)&Vs[nb][srow][vp1] = va;
            *(u32x2*)&Vs[nb][srow][vp2] = vb2;
        }
    }

    // ---- epilogue ----
    lsum += __shfl_xor(lsum, 16);
    lsum += __shfl_xor(lsum, 32);
    const float inv = 1.0f / lsum;
    #pragma unroll
    for (int dt = 0; dt < 4; ++dt) {
        u32x2 pw;
        pw[0] = pk2bf(O[dt][0] * inv, O[dt][1] * inv);
        pw[1] = pk2bf(O[dt][2] * inv, O[dt][3] * inv);
        const int pc = ((2 * dt + (quad >> 1)) ^ xk) * 8 + (quad & 1) * 4;
        *(u32x2*)&Ps[wv][n][pc] = pw;
    }
    __builtin_amdgcn_s_waitcnt(0);            // lgkmcnt for own-wave Ps writes
    const int fr = lane >> 3;                        // 0..7
    const int c8l = lane & 7;                        // logical chunk
    #pragma unroll
    for (int it = 0; it < 2; ++it) {
        const int row = it * 8 + fr;                 // 0..15, row&7 == fr
        const int q   = q0 + wv * 16 + row;
        unsigned short* op = ot + ((long)(b * S_ + q) * H_ + h) * DK_ + c8l * 8;
        *(bf16x8*)op = *(const bf16x8*)&Ps[wv][row][(c8l ^ fr) * 8];
    }
}

// ---------------------------------------------------------------------------
extern "C" void kernel_launch(void* const* d_in, const int* in_sizes, int n_in,
                              void* d_out, int out_size, void* d_ws, size_t ws_size,
                              hipStream_t stream)
{
    const float* x  = (const float*)d_in[0];
    const float* Wq = (const float*)d_in[2];
    const float* bq = (const float*)d_in[3];
    const float* Wk = (const float*)d_in[4];
    const float* bk = (const float*)d_in[5];
    const float* Wv = (const float*)d_in[6];
    const float* bv = (const float*)d_in[7];
    const float* Wo = (const float*)d_in[8];
    const float* bo = (const float*)d_in[9];
    float* out = (float*)d_out;

    // Workspace (bf16 shorts + f32 table), ~39.3 MB. ob aliases qkvm.
    unsigned short* ws    = (unsigned short*)d_ws;
    unsigned short* xb    = ws;                   // 4194304
    unsigned short* qkvm  = xb + 4194304;         // 6291456  (ob alias only)
    unsigned short* qbuf  = qkvm + 6291456;       // 4194304
    unsigned short* kbuf  = qbuf + 4194304;       // 1048576
    unsigned short* vbuf  = kbuf + 1048576;       // 1048576
    unsigned short* WqkvT = vbuf + 1048576;       // 1572864
    unsigned short* WoT   = WqkvT + 1572864;      // 1048576
    float*          sct   = (float*)(WoT + 1048576); // 131072 floats (512KB)
    unsigned short* ob    = qkvm;                 // alias

    prep_kernel<<<2944, 256, 0, stream>>>(x, Wq, Wk, Wv, Wo, xb, WqkvT, WoT, sct);

    gemm64_kernel<true><<<dim3(64, 12), 256, 0, stream>>>(
        xb, WqkvT, bq, bk, bv, nullptr, vbuf, qbuf, kbuf, sct, 1536, 1024);

    attn_kernel<<<512, 512, 0, stream>>>(qbuf, kbuf, vbuf, ob);

    gemm64_kernel<false><<<dim3(64, 8), 256, 0, stream>>>(
        ob, WoT, bo, nullptr, nullptr, out, nullptr, nullptr, nullptr, nullptr,
        1024, 1024);
}